// Round 1
// baseline (2301.512 us; speedup 1.0000x reference)
//
#include <hip/hip_runtime.h>

#define N2 2048      // B*P
#define N8 8192      // B*P*UP
#define CDIM 384
#define H1C 192      // C/2
#define H2C 96       // C/4
#define PDIM 512
#define KR 16
#define FOLDH 256

__device__ __forceinline__ float frelu(float x) { return x > 0.f ? x : 0.f; }

// ---------------- top-k insertion (register-resident, compile-time indices) --------
template<int KSEL>
__device__ __forceinline__ void topk_insert(float (&bd)[KSEL], int (&bi)[KSEL], float dv, int col) {
    // reject vs current worst
    if (dv > bd[KSEL-1] || (dv == bd[KSEL-1] && col >= bi[KSEL-1])) return;
    #pragma unroll
    for (int s = KSEL-1; s >= 0; --s) {
        bool better = (dv < bd[s]) || (dv == bd[s] && col < bi[s]);
        if (better) {
            if (s + 1 < KSEL) { bd[s+1] = bd[s]; bi[s+1] = bi[s]; }
            bd[s] = dv; bi[s] = col;
        }
    }
}

// ---------------- row squared norms ------------------------------------------------
__global__ void rowsq_kernel(const float* __restrict__ x, float* __restrict__ sq, int n, int d) {
    int row = blockIdx.x;
    int tid = threadIdx.x;
    __shared__ float red[256];
    float acc = 0.f;
    for (int k = tid; k < d; k += 256) { float v = x[row*d + k]; acc += v*v; }
    red[tid] = acc; __syncthreads();
    for (int s = 128; s > 0; s >>= 1) { if (tid < s) red[tid] += red[tid+s]; __syncthreads(); }
    if (tid == 0) sq[row] = red[0];
}

// ---------------- pairwise distance matrix: d = sq_i + sq_j - 2*dot ---------------
__global__ void dist_kernel(const float* __restrict__ x, const float* __restrict__ sq,
                            float* __restrict__ dist, int n, int d) {
    __shared__ float As[16][17];
    __shared__ float Bs[16][17];
    int ty = threadIdx.y, tx = threadIdx.x;
    int row = blockIdx.y*16 + ty;
    int col = blockIdx.x*16 + tx;
    float acc = 0.f;
    for (int k0 = 0; k0 < d; k0 += 16) {
        As[ty][tx] = (k0+tx < d) ? x[(blockIdx.y*16+ty)*d + k0+tx] : 0.f;
        Bs[ty][tx] = (k0+tx < d) ? x[(blockIdx.x*16+ty)*d + k0+tx] : 0.f;
        __syncthreads();
        #pragma unroll
        for (int kk = 0; kk < 16; ++kk) acc += As[ty][kk]*Bs[tx][kk];
        __syncthreads();
    }
    dist[row*n + col] = sq[row] + sq[col] - 2.f*acc;
}

// ---------------- knn from materialized dist matrix (wave per row) ----------------
template<int KSEL>
__global__ void knn_dist_kernel(const float* __restrict__ dist, int n, int* __restrict__ out_idx) {
    int wave = threadIdx.x >> 6;
    int lane = threadIdx.x & 63;
    int row = blockIdx.x*4 + wave;
    __shared__ float ld[4][64*KSEL];
    __shared__ int   li[4][64*KSEL];
    float bd[KSEL]; int bi[KSEL];
    #pragma unroll
    for (int s = 0; s < KSEL; ++s) { bd[s] = 3.0e38f; bi[s] = 0x7fffffff; }
    for (int col = lane; col < n; col += 64) {
        if (col == row) continue;
        float dv = dist[(size_t)row*n + col];
        topk_insert<KSEL>(bd, bi, dv, col);
    }
    #pragma unroll
    for (int s = 0; s < KSEL; ++s) { ld[wave][lane*KSEL+s] = bd[s]; li[wave][lane*KSEL+s] = bi[s]; }
    __syncthreads();
    if (lane == 0) {
        float md[KSEL]; int mi[KSEL];
        #pragma unroll
        for (int s = 0; s < KSEL; ++s) { md[s] = 3.0e38f; mi[s] = 0x7fffffff; }
        for (int e = 0; e < 64*KSEL; ++e) {
            int ci = li[wave][e];
            if (ci == 0x7fffffff) continue;
            topk_insert<KSEL>(md, mi, ld[wave][e], ci);
        }
        for (int s = 0; s < KSEL; ++s) out_idx[row*KSEL+s] = mi[s];
    }
}

// ---------------- knn over xyz (3-dim, on the fly) --------------------------------
__global__ void knn_xyz_kernel(const float* __restrict__ xyz, const float* __restrict__ sq,
                               int n, int* __restrict__ out_idx) {
    int wave = threadIdx.x >> 6;
    int lane = threadIdx.x & 63;
    int row = blockIdx.x*4 + wave;
    __shared__ float ld[4][64*16];
    __shared__ int   li[4][64*16];
    float x0 = xyz[row*3], x1 = xyz[row*3+1], x2 = xyz[row*3+2];
    float sr = sq[row];
    float bd[16]; int bi[16];
    #pragma unroll
    for (int s = 0; s < 16; ++s) { bd[s] = 3.0e38f; bi[s] = 0x7fffffff; }
    for (int col = lane; col < n; col += 64) {
        if (col == row) continue;
        float dv = sr + sq[col] - 2.f*(x0*xyz[col*3] + x1*xyz[col*3+1] + x2*xyz[col*3+2]);
        topk_insert<16>(bd, bi, dv, col);
    }
    #pragma unroll
    for (int s = 0; s < 16; ++s) { ld[wave][lane*16+s] = bd[s]; li[wave][lane*16+s] = bi[s]; }
    __syncthreads();
    if (lane == 0) {
        float md[16]; int mi[16];
        #pragma unroll
        for (int s = 0; s < 16; ++s) { md[s] = 3.0e38f; mi[s] = 0x7fffffff; }
        for (int e = 0; e < 64*16; ++e) {
            int ci = li[wave][e];
            if (ci == 0x7fffffff) continue;
            topk_insert<16>(md, mi, ld[wave][e], ci);
        }
        for (int s = 0; s < 16; ++s) out_idx[row*16+s] = mi[s];
    }
}

// ---------------- generic small GEMM: C = A[n,K] @ B[K,m] (+bias) -----------------
__global__ void gemm_kernel(const float* __restrict__ A, const float* __restrict__ Bw,
                            const float* __restrict__ bias, float* __restrict__ Cout,
                            int n, int m, int K) {
    __shared__ float As[16][17], Bs[16][17];
    int ty = threadIdx.y, tx = threadIdx.x;
    int row = blockIdx.y*16 + ty;
    int col = blockIdx.x*16 + tx;
    float acc = 0.f;
    for (int k0 = 0; k0 < K; k0 += 16) {
        As[ty][tx] = (row < n && k0+tx < K) ? A[(size_t)row*K + k0+tx] : 0.f;
        Bs[ty][tx] = (k0+ty < K && col < m) ? Bw[(size_t)(k0+ty)*m + col] : 0.f;
        __syncthreads();
        #pragma unroll
        for (int kk = 0; kk < 16; ++kk) acc += As[ty][kk]*Bs[kk][tx];
        __syncthreads();
    }
    if (row < n && col < m) Cout[(size_t)row*m + col] = acc + (bias ? bias[col] : 0.f);
}

// ---------------- W1a - W1b (halves of concatenated-input weight) -----------------
__global__ void matsub_kernel(const float* __restrict__ w, float* __restrict__ out, int count) {
    int i = blockIdx.x*256 + threadIdx.x;
    if (i < count) out[i] = w[i] - w[count + i];
}

// ---------------- EdgeConv: out[i] = max_j relu(u_i + v_j) @ W2 + b2 --------------
template<int H1, int H2, int KN, int SELF>
__global__ void edge_mlp_max_kernel(const float* __restrict__ u, const float* __restrict__ v,
                                    const float* __restrict__ w2, const float* __restrict__ b2,
                                    const int* __restrict__ idx, float* __restrict__ out) {
    int i = blockIdx.x;
    int tid = threadIdx.x;
    __shared__ float su[H1], st[H1];
    for (int h = tid; h < H1; h += 256) su[h] = u[(size_t)i*H1 + h];
    float best = -3.0e38f;
    const int TOT = KN + SELF;
    for (int e = 0; e < TOT; ++e) {
        int j = (SELF && e == 0) ? i : idx[i*KN + (e - SELF)];
        __syncthreads();
        for (int h = tid; h < H1; h += 256) st[h] = frelu(su[h] + v[(size_t)j*H1 + h]);
        __syncthreads();
        if (tid < H2) {
            float acc = 0.f;
            for (int h = 0; h < H1; ++h) acc += st[h]*w2[h*H2 + tid];
            best = fmaxf(best, acc + b2[tid]);
        }
    }
    if (tid < H2) out[(size_t)i*H2 + tid] = best;
}

// ---------------- refiner EdgeConv (H1=384, H2=3), wave per point -----------------
__global__ void edge_ref_kernel(const float* __restrict__ ur, const float* __restrict__ vr,
                                const float* __restrict__ w2, const float* __restrict__ b2,
                                const int* __restrict__ idx,
                                const float* __restrict__ xyz_in, float* __restrict__ out, int n) {
    int wave = threadIdx.x >> 6, lane = threadIdx.x & 63;
    int i = blockIdx.x*4 + wave;
    if (i >= n) return;
    float m0 = -3.0e38f, m1 = -3.0e38f, m2 = -3.0e38f;
    float uh[6];
    #pragma unroll
    for (int t = 0; t < 6; ++t) uh[t] = ur[(size_t)i*384 + lane + 64*t];
    for (int e = 0; e < KR; ++e) {
        int j = idx[i*KR + e];
        float a0 = 0.f, a1 = 0.f, a2 = 0.f;
        #pragma unroll
        for (int t = 0; t < 6; ++t) {
            int h = lane + 64*t;
            float tv = frelu(uh[t] + vr[(size_t)j*384 + h]);
            a0 += tv*w2[h*3+0]; a1 += tv*w2[h*3+1]; a2 += tv*w2[h*3+2];
        }
        #pragma unroll
        for (int s = 32; s > 0; s >>= 1) {
            a0 += __shfl_xor(a0, s); a1 += __shfl_xor(a1, s); a2 += __shfl_xor(a2, s);
        }
        m0 = fmaxf(m0, a0 + b2[0]); m1 = fmaxf(m1, a1 + b2[1]); m2 = fmaxf(m2, a2 + b2[2]);
    }
    if (lane == 0) {
        out[i*3+0] = xyz_in[i*3+0] + m0;
        out[i*3+1] = xyz_in[i*3+1] + m1;
        out[i*3+2] = xyz_in[i*3+2] + m2;
    }
}

// ---------------- target xyz: repeat(pred,4) + 0.02*noise -------------------------
__global__ void tgt0_kernel(const float* __restrict__ pred_xyz, const float* __restrict__ noise,
                            float* __restrict__ xyz0) {
    int i = blockIdx.x*256 + threadIdx.x;
    if (i >= N8*3) return;
    int pt = i/3, c = i - pt*3;
    int b = pt >> 11, r = pt & 2047, p = r >> 2;
    xyz0[i] = pred_xyz[(b*PDIM + p)*3 + c] + 0.02f*noise[i];
}

// ---------------- folding MLP: 99 -> 256 -> 256 -> 3 residual ---------------------
__global__ void fold_kernel(const float* __restrict__ xyz0, const float* __restrict__ featd,
                            const float* __restrict__ w1, const float* __restrict__ b1,
                            const float* __restrict__ w2, const float* __restrict__ b2,
                            const float* __restrict__ w3, const float* __restrict__ b3,
                            float* __restrict__ xyz1) {
    const int PTS = 16;
    int base = blockIdx.x * PTS;
    int tid = threadIdx.x;
    __shared__ float xin[PTS][100];
    __shared__ float h1[PTS][FOLDH];
    __shared__ float h2[PTS][FOLDH];
    for (int t = tid; t < PTS*99; t += 256) {
        int pt = t/99, k = t - pt*99;
        int gi = base + pt;
        float v;
        if (k < 3) v = xyz0[gi*3 + k];
        else {
            int b = gi >> 11, r = gi & 2047, p = r >> 2;
            v = featd[(b*PDIM + p)*H2C + (k - 3)];
        }
        xin[pt][k] = v;
    }
    __syncthreads();
    {
        int c = tid;
        float acc[PTS];
        #pragma unroll
        for (int pt = 0; pt < PTS; ++pt) acc[pt] = b1[c];
        for (int k = 0; k < 99; ++k) {
            float wv = w1[k*FOLDH + c];
            #pragma unroll
            for (int pt = 0; pt < PTS; ++pt) acc[pt] += xin[pt][k]*wv;
        }
        #pragma unroll
        for (int pt = 0; pt < PTS; ++pt) h1[pt][c] = frelu(acc[pt]);
    }
    __syncthreads();
    {
        int c = tid;
        float acc[PTS];
        #pragma unroll
        for (int pt = 0; pt < PTS; ++pt) acc[pt] = b2[c];
        for (int k = 0; k < FOLDH; ++k) {
            float wv = w2[k*FOLDH + c];
            #pragma unroll
            for (int pt = 0; pt < PTS; ++pt) acc[pt] += h1[pt][k]*wv;
        }
        #pragma unroll
        for (int pt = 0; pt < PTS; ++pt) h2[pt][c] = frelu(acc[pt]);
    }
    __syncthreads();
    if (tid < PTS*3) {
        int pt = tid/3, c = tid - pt*3;
        float acc = b3[c];
        for (int k = 0; k < FOLDH; ++k) acc += h2[pt][k]*w3[k*3 + c];
        int gi = base + pt;
        xyz1[gi*3 + c] = xyz0[gi*3 + c] + acc;
    }
}

// ---------------- ctx deform head: xyz + 0.05 * mlp2(feat) ------------------------
__global__ void cdef_kernel(const float* __restrict__ feat, const float* __restrict__ w1,
                            const float* __restrict__ b1, const float* __restrict__ w2,
                            const float* __restrict__ b2, const float* __restrict__ ctx_xyz,
                            float* __restrict__ out) {
    int i = blockIdx.x;
    int tid = threadIdx.x; // 128
    __shared__ float sf[H2C], st[H2C];
    if (tid < H2C) sf[tid] = feat[(size_t)i*H2C + tid];
    __syncthreads();
    if (tid < H2C) {
        float acc = b1[tid];
        for (int k = 0; k < H2C; ++k) acc += sf[k]*w1[k*H2C + tid];
        st[tid] = frelu(acc);
    }
    __syncthreads();
    if (tid < 3) {
        float acc = b2[tid];
        for (int k = 0; k < H2C; ++k) acc += st[k]*w2[k*3 + tid];
        out[i*3 + tid] = ctx_xyz[i*3 + tid] + 0.05f*acc;
    }
}

// ---------------- xcat = [tgt_feat(96), tgt_xyz(3)] -------------------------------
__global__ void xcat_kernel(const float* __restrict__ featd, const float* __restrict__ xyz1,
                            float* __restrict__ xcat) {
    int i = blockIdx.x*256 + threadIdx.x;
    if (i >= N8*99) return;
    int pt = i/99, k = i - pt*99;
    float v;
    if (k < 96) {
        int b = pt >> 11, r = pt & 2047, p = r >> 2;
        v = featd[(b*PDIM + p)*H2C + k];
    } else {
        v = xyz1[pt*3 + (k - 96)];
    }
    xcat[i] = v;
}

extern "C" void kernel_launch(void* const* d_in, const int* in_sizes, int n_in,
                              void* d_out, int out_size, void* d_ws, size_t ws_size,
                              hipStream_t stream) {
    const float* ctx_xyz    = (const float*)d_in[0];
    const float* ctx_tokens = (const float*)d_in[1];
    const float* pred_xyz   = (const float*)d_in[2];
    const float* noise      = (const float*)d_in[4];
    const float* c1w1 = (const float*)d_in[5];
    const float* c1b1 = (const float*)d_in[6];
    const float* c1w2 = (const float*)d_in[7];
    const float* c1b2 = (const float*)d_in[8];
    const float* c2w1 = (const float*)d_in[9];
    const float* c2b1 = (const float*)d_in[10];
    const float* c2w2 = (const float*)d_in[11];
    const float* c2b2 = (const float*)d_in[12];
    const float* cdw1 = (const float*)d_in[13];
    const float* cdb1 = (const float*)d_in[14];
    const float* cdw2 = (const float*)d_in[15];
    const float* cdb2 = (const float*)d_in[16];
    const float* fw1  = (const float*)d_in[17];
    const float* fb1  = (const float*)d_in[18];
    const float* fw2  = (const float*)d_in[19];
    const float* fb2  = (const float*)d_in[20];
    const float* fw3  = (const float*)d_in[21];
    const float* fb3  = (const float*)d_in[22];
    const float* rw1  = (const float*)d_in[23];
    const float* rb1  = (const float*)d_in[24];
    const float* rw2  = (const float*)d_in[25];
    const float* rb2  = (const float*)d_in[26];

    float* W = (float*)d_ws;
    // element offsets (staged aliasing: dist/u1..ctx_feat region reused by ur/vr)
    float* dist   = W + 0;                   // 2048*2048 = 4,194,304
    float* ur     = W + 0;                   // 8192*384  = 3,145,728 (after dist dead)
    float* vr     = W + 3145728;             // ends 6,291,456
    float* u1     = W + 4194304;             // 2048*192
    float* v1     = u1 + N2*H1C;
    float* h_ctx  = v1 + N2*H1C;
    float* h_tgt  = h_ctx + N2*H1C;
    float* u2     = h_tgt + N2*H1C;          // 2048*96
    float* v2     = u2 + N2*H2C;
    float* cfeat  = v2 + N2*H2C;             // ends elem 6,356,992
    float* tfeat  = W + 6356992;             // persistent from here
    float* wd1    = tfeat + N2*H2C;          // 384*192
    float* wd2    = wd1 + 384*192;           // 192*96
    float* wdr    = wd2 + 192*96;            // 99*384
    int*   cidx1  = (int*)(wdr + 99*384);    // 2048*16
    int*   tidx1  = cidx1 + N2*16;           // 2048*4
    int*   cidx2  = tidx1 + N2*4;            // 2048*8
    int*   tidx2  = cidx2 + N2*8;            // 2048*2
    int*   ridx   = tidx2 + N2*2;            // 8192*16
    float* sqb    = (float*)(ridx + N8*16);  // 8192
    float* xyz0   = sqb + N8;                // 8192*3
    float* xyz1   = xyz0 + N8*3;             // 8192*3
    float* xcat   = xyz1 + N8*3;             // 8192*99

    float* out_ctx = (float*)d_out;          // rows 0..2047
    float* out_tgt = out_ctx + N2*3;         // rows 2048..10239

    dim3 b16(16,16);

    // --- weight diffs: Wa - Wb for the [xi, xj-xi] factorization
    matsub_kernel<<<(384*192+255)/256, 256, 0, stream>>>(c1w1, wd1, 384*192);
    matsub_kernel<<<(192*96 +255)/256, 256, 0, stream>>>(c2w1, wd2, 192*96);
    matsub_kernel<<<(99*384 +255)/256, 256, 0, stream>>>(rw1,  wdr, 99*384);

    // --- S1: token distance matrix (shared by ctx knn-16 and tgt distinct knn-4)
    rowsq_kernel<<<N2, 256, 0, stream>>>(ctx_tokens, sqb, N2, CDIM);
    dist_kernel<<<dim3(N2/16, N2/16), b16, 0, stream>>>(ctx_tokens, sqb, dist, N2, CDIM);
    knn_dist_kernel<16><<<N2/4, 256, 0, stream>>>(dist, N2, cidx1);
    knn_dist_kernel<4> <<<N2/4, 256, 0, stream>>>(dist, N2, tidx1);

    // --- S2: conv1 u/v precompute + edge max (ctx: 16 nbrs; tgt: self + 4 distinct)
    gemm_kernel<<<dim3(H1C/16, N2/16), b16, 0, stream>>>(ctx_tokens, wd1, c1b1, u1, N2, H1C, CDIM);
    gemm_kernel<<<dim3(H1C/16, N2/16), b16, 0, stream>>>(ctx_tokens, c1w1 + 384*192, nullptr, v1, N2, H1C, CDIM);
    edge_mlp_max_kernel<192,192,16,0><<<N2, 256, 0, stream>>>(u1, v1, c1w2, c1b2, cidx1, h_ctx);
    edge_mlp_max_kernel<192,192,4, 1><<<N2, 256, 0, stream>>>(u1, v1, c1w2, c1b2, tidx1, h_tgt);

    // --- S3: ctx conv2 + deform head
    rowsq_kernel<<<N2, 256, 0, stream>>>(h_ctx, sqb, N2, H1C);
    dist_kernel<<<dim3(N2/16, N2/16), b16, 0, stream>>>(h_ctx, sqb, dist, N2, H1C);
    knn_dist_kernel<8><<<N2/4, 256, 0, stream>>>(dist, N2, cidx2);
    gemm_kernel<<<dim3(H2C/16, N2/16), b16, 0, stream>>>(h_ctx, wd2, c2b1, u2, N2, H2C, H1C);
    gemm_kernel<<<dim3(H2C/16, N2/16), b16, 0, stream>>>(h_ctx, c2w1 + 192*96, nullptr, v2, N2, H2C, H1C);
    edge_mlp_max_kernel<96,96,8,0><<<N2, 256, 0, stream>>>(u2, v2, c2w2, c2b2, cidx2, cfeat);
    cdef_kernel<<<N2, 128, 0, stream>>>(cfeat, cdw1, cdb1, cdw2, cdb2, ctx_xyz, out_ctx);

    // --- S4: tgt conv2 (distinct: self + 2)
    rowsq_kernel<<<N2, 256, 0, stream>>>(h_tgt, sqb, N2, H1C);
    dist_kernel<<<dim3(N2/16, N2/16), b16, 0, stream>>>(h_tgt, sqb, dist, N2, H1C);
    knn_dist_kernel<2><<<N2/4, 256, 0, stream>>>(dist, N2, tidx2);
    gemm_kernel<<<dim3(H2C/16, N2/16), b16, 0, stream>>>(h_tgt, wd2, c2b1, u2, N2, H2C, H1C);
    gemm_kernel<<<dim3(H2C/16, N2/16), b16, 0, stream>>>(h_tgt, c2w1 + 192*96, nullptr, v2, N2, H2C, H1C);
    edge_mlp_max_kernel<96,96,2,1><<<N2, 256, 0, stream>>>(u2, v2, c2w2, c2b2, tidx2, tfeat);

    // --- S6: target xyz upsample + folding MLP
    tgt0_kernel<<<(N8*3+255)/256, 256, 0, stream>>>(pred_xyz, noise, xyz0);
    fold_kernel<<<N8/16, 256, 0, stream>>>(xyz0, tfeat, fw1, fb1, fw2, fb2, fw3, fb3, xyz1);

    // --- S7: refiner knn over xyz (full 8192, no duplicates here)
    rowsq_kernel<<<N8, 256, 0, stream>>>(xyz1, sqb, N8, 3);
    knn_xyz_kernel<<<N8/4, 256, 0, stream>>>(xyz1, sqb, N8, ridx);

    // --- S8: refiner EdgeConv (u/v precompute via xcat GEMMs), residual to output
    xcat_kernel<<<(N8*99+255)/256, 256, 0, stream>>>(tfeat, xyz1, xcat);
    gemm_kernel<<<dim3(384/16, N8/16), b16, 0, stream>>>(xcat, wdr, rb1, ur, N8, 384, 99);
    gemm_kernel<<<dim3(384/16, N8/16), b16, 0, stream>>>(xcat, rw1 + 99*384, nullptr, vr, N8, 384, 99);
    edge_ref_kernel<<<N8/4, 256, 0, stream>>>(ur, vr, rw2, rb2, ridx, xyz1, out_tgt, N8);
}

// Round 3
// 851.012 us; speedup vs baseline: 2.7044x; 2.7044x over previous
//
#include <hip/hip_runtime.h>

#define N2 2048      // B*P
#define N8 8192      // B*P*UP
#define CDIM 384
#define H1C 192      // C/2
#define H2C 96       // C/4
#define PDIM 512
#define KRR 16
#define FOLDH 256
#define XCAP 256

__device__ __forceinline__ float frelu(float x) { return x > 0.f ? x : 0.f; }

// ---------------- row squared norms ------------------------------------------------
__global__ void rowsq_kernel(const float* __restrict__ x, float* __restrict__ sq, int n, int d) {
    int row = blockIdx.x;
    int tid = threadIdx.x;
    __shared__ float red[256];
    float acc = 0.f;
    for (int k = tid; k < d; k += 256) { float v = x[row*d + k]; acc += v*v; }
    red[tid] = acc; __syncthreads();
    for (int s = 128; s > 0; s >>= 1) { if (tid < s) red[tid] += red[tid+s]; __syncthreads(); }
    if (tid == 0) sq[row] = red[0];
}

// ---------------- pairwise distance matrix, 64x64 tile, 4x4 micro ------------------
__global__ void dist64_kernel(const float* __restrict__ x, const float* __restrict__ sq,
                              float* __restrict__ dist, int n, int K) {
    __shared__ __align__(16) float As[16][68];
    __shared__ __align__(16) float Bs[16][68];
    int tx = threadIdx.x, ty = threadIdx.y;
    int t = ty*16 + tx;
    int row0 = blockIdx.y*64, col0 = blockIdx.x*64;
    float acc[4][4] = {};
    for (int k0 = 0; k0 < K; k0 += 16) {
        #pragma unroll
        for (int r = 0; r < 4; ++r) {
            int e = t + 256*r; int kk = e & 15, mm = e >> 4;
            As[kk][mm] = x[(size_t)(row0+mm)*K + k0+kk];
            Bs[kk][mm] = x[(size_t)(col0+mm)*K + k0+kk];
        }
        __syncthreads();
        #pragma unroll
        for (int kk = 0; kk < 16; ++kk) {
            float4 a4 = *(const float4*)&As[kk][ty*4];
            float4 b4 = *(const float4*)&Bs[kk][tx*4];
            acc[0][0] += a4.x*b4.x; acc[0][1] += a4.x*b4.y; acc[0][2] += a4.x*b4.z; acc[0][3] += a4.x*b4.w;
            acc[1][0] += a4.y*b4.x; acc[1][1] += a4.y*b4.y; acc[1][2] += a4.y*b4.z; acc[1][3] += a4.y*b4.w;
            acc[2][0] += a4.z*b4.x; acc[2][1] += a4.z*b4.y; acc[2][2] += a4.z*b4.z; acc[2][3] += a4.z*b4.w;
            acc[3][0] += a4.w*b4.x; acc[3][1] += a4.w*b4.y; acc[3][2] += a4.w*b4.z; acc[3][3] += a4.w*b4.w;
        }
        __syncthreads();
    }
    #pragma unroll
    for (int i2 = 0; i2 < 4; ++i2) {
        int row = row0 + ty*4 + i2;
        float sr = sq[row];
        float4 o;
        o.x = sr + sq[col0+tx*4+0] - 2.f*acc[i2][0];
        o.y = sr + sq[col0+tx*4+1] - 2.f*acc[i2][1];
        o.z = sr + sq[col0+tx*4+2] - 2.f*acc[i2][2];
        o.w = sr + sq[col0+tx*4+3] - 2.f*acc[i2][3];
        *(float4*)&dist[(size_t)row*n + col0 + tx*4] = o;
    }
}

// ---------------- GEMM: C = A[rows,K] @ B[K,m] (+bias), 64x64 tile ------------------
__global__ void gemm64_kernel(const float* __restrict__ A, const float* __restrict__ Bw,
                              const float* __restrict__ bias, float* __restrict__ Cout,
                              int m, int K) {
    __shared__ __align__(16) float As[16][68];
    __shared__ __align__(16) float Bs[16][68];
    int tx = threadIdx.x, ty = threadIdx.y;
    int t = ty*16 + tx;
    int row0 = blockIdx.y*64, col0 = blockIdx.x*64;
    float acc[4][4] = {};
    for (int k0 = 0; k0 < K; k0 += 16) {
        #pragma unroll
        for (int r = 0; r < 4; ++r) {
            int e = t + 256*r; int kk = e & 15, mm = e >> 4;
            As[kk][mm] = (k0 + kk < K) ? A[(size_t)(row0+mm)*K + k0+kk] : 0.f;
        }
        #pragma unroll
        for (int r = 0; r < 4; ++r) {
            int e = t + 256*r; int nn = e & 63, kk = e >> 6;
            int col = col0 + nn;
            Bs[kk][nn] = (k0 + kk < K && col < m) ? Bw[(size_t)(k0+kk)*m + col] : 0.f;
        }
        __syncthreads();
        #pragma unroll
        for (int kk = 0; kk < 16; ++kk) {
            float4 a4 = *(const float4*)&As[kk][ty*4];
            float4 b4 = *(const float4*)&Bs[kk][tx*4];
            acc[0][0] += a4.x*b4.x; acc[0][1] += a4.x*b4.y; acc[0][2] += a4.x*b4.z; acc[0][3] += a4.x*b4.w;
            acc[1][0] += a4.y*b4.x; acc[1][1] += a4.y*b4.y; acc[1][2] += a4.y*b4.z; acc[1][3] += a4.y*b4.w;
            acc[2][0] += a4.z*b4.x; acc[2][1] += a4.z*b4.y; acc[2][2] += a4.z*b4.z; acc[2][3] += a4.z*b4.w;
            acc[3][0] += a4.w*b4.x; acc[3][1] += a4.w*b4.y; acc[3][2] += a4.w*b4.z; acc[3][3] += a4.w*b4.w;
        }
        __syncthreads();
    }
    #pragma unroll
    for (int i2 = 0; i2 < 4; ++i2) {
        int row = row0 + ty*4 + i2;
        #pragma unroll
        for (int j2 = 0; j2 < 4; ++j2) {
            int col = col0 + tx*4 + j2;
            if (col < m) Cout[(size_t)row*m + col] = acc[i2][j2] + (bias ? bias[col] : 0.f);
        }
    }
}

// ---------------- W1a - W1b --------------------------------------------------------
__global__ void matsub_kernel(const float* __restrict__ w, float* __restrict__ out, int count) {
    int i = blockIdx.x*256 + threadIdx.x;
    if (i < count) out[i] = w[i] - w[count + i];
}

// ---------------- pack xyz + sq into float4 ----------------------------------------
__global__ void pack_xyz_kernel(const float* __restrict__ xyz, float4* __restrict__ packed, int n) {
    int i = blockIdx.x*256 + threadIdx.x;
    if (i < n) {
        float x = xyz[i*3], y = xyz[i*3+1], z = xyz[i*3+2];
        packed[i] = make_float4(x, y, z, x*x + y*y + z*z);
    }
}

// ---------------- exact two-phase knn over packed xyz ------------------------------
__global__ void knn_xyz2_kernel(const float4* __restrict__ pts, int n, int* __restrict__ out_idx) {
    int wave = threadIdx.x >> 6, lane = threadIdx.x & 63;
    int row = blockIdx.x*4 + wave;
    __shared__ float bufd[4][XCAP];
    __shared__ int   bufi[4][XCAP];
    float4 p = pts[row];
    float x0 = p.x, x1 = p.y, x2 = p.z, sr = p.w;
    // Phase A: per-lane min
    float mv = 3.0e38f; int mi = 0x7fffffff;
    for (int col = lane; col < n; col += 64) {
        if (col == row) continue;
        float4 q = pts[col];
        float dv = sr + q.w - 2.f*(x0*q.x + x1*q.y + x2*q.z);
        if (dv < mv || (dv == mv && col < mi)) { mv = dv; mi = col; }
    }
    // 16th smallest of lane-minima -> threshold (upper bound on global 16th)
    float cv = mv; int ci = mi;
    float Tv = 0.f; int Ti = 0;
    for (int r = 0; r < 16; ++r) {
        float wv = cv; int wi = ci;
        #pragma unroll
        for (int s = 1; s < 64; s <<= 1) {
            float ov = __shfl_xor(wv, s); int oi = __shfl_xor(wi, s);
            if (ov < wv || (ov == wv && oi < wi)) { wv = ov; wi = oi; }
        }
        Tv = wv; Ti = wi;
        if (cv == wv && ci == wi) { cv = 3.0e38f; ci = 0x7fffffff; }
    }
    // Phase B: collect all (d,col) <=lex (Tv,Ti)
    int cnt = 0;
    for (int col = lane; col < n; col += 64) {
        float4 q = pts[col];
        float dv = sr + q.w - 2.f*(x0*q.x + x1*q.y + x2*q.z);
        bool keep = (col != row) && (dv < Tv || (dv == Tv && col <= Ti));
        unsigned long long m = __ballot(keep);
        int pos = cnt + __popcll(m & ((1ull << lane) - 1ull));
        if (keep && pos < XCAP) { bufd[wave][pos] = dv; bufi[wave][pos] = col; }
        cnt += (int)__popcll(m);
    }
    if (cnt > XCAP) cnt = XCAP;
    __syncthreads();
    // Phase C: 16 rounds of wave argmin
    float cd[4]; int cix[4];
    #pragma unroll
    for (int s = 0; s < 4; ++s) {
        int c = lane + 64*s;
        bool v = c < cnt;
        cd[s]  = v ? bufd[wave][c] : 3.0e38f;
        cix[s] = v ? bufi[wave][c] : 0x7fffffff;
    }
    for (int r = 0; r < 16; ++r) {
        float lv = cd[0]; int li_ = cix[0];
        #pragma unroll
        for (int s = 1; s < 4; ++s) {
            if (cd[s] < lv || (cd[s] == lv && cix[s] < li_)) { lv = cd[s]; li_ = cix[s]; }
        }
        float wv = lv; int wi = li_;
        #pragma unroll
        for (int s = 1; s < 64; s <<= 1) {
            float ov = __shfl_xor(wv, s); int oi = __shfl_xor(wi, s);
            if (ov < wv || (ov == wv && oi < wi)) { wv = ov; wi = oi; }
        }
        if (lane == 0) {
            int safe = ((unsigned)wi < (unsigned)n) ? wi : ((row + 1) & (n - 1));
            out_idx[row*16 + r] = safe;
        }
        #pragma unroll
        for (int s = 0; s < 4; ++s) {
            if (cd[s] == wv && cix[s] == wi) { cd[s] = 3.0e38f; cix[s] = 0x7fffffff; }
        }
    }
}

// ---------------- exact two-phase knn from materialized dist row -------------------
template<int KSEL>
__global__ void knn_dist2_kernel(const float* __restrict__ dist, int n, int* __restrict__ out_idx) {
    int wave = threadIdx.x >> 6, lane = threadIdx.x & 63;
    int row = blockIdx.x*4 + wave;
    __shared__ float bufd[4][XCAP];
    __shared__ int   bufi[4][XCAP];
    const float* drow = dist + (size_t)row*n;
    float mv = 3.0e38f; int mi = 0x7fffffff;
    for (int col = lane; col < n; col += 64) {
        if (col == row) continue;
        float dv = drow[col];
        if (dv < mv || (dv == mv && col < mi)) { mv = dv; mi = col; }
    }
    float cv = mv; int ci = mi;
    float Tv = 0.f; int Ti = 0;
    for (int r = 0; r < KSEL; ++r) {
        float wv = cv; int wi = ci;
        #pragma unroll
        for (int s = 1; s < 64; s <<= 1) {
            float ov = __shfl_xor(wv, s); int oi = __shfl_xor(wi, s);
            if (ov < wv || (ov == wv && oi < wi)) { wv = ov; wi = oi; }
        }
        Tv = wv; Ti = wi;
        if (cv == wv && ci == wi) { cv = 3.0e38f; ci = 0x7fffffff; }
    }
    int cnt = 0;
    for (int col = lane; col < n; col += 64) {
        float dv = drow[col];
        bool keep = (col != row) && (dv < Tv || (dv == Tv && col <= Ti));
        unsigned long long m = __ballot(keep);
        int pos = cnt + __popcll(m & ((1ull << lane) - 1ull));
        if (keep && pos < XCAP) { bufd[wave][pos] = dv; bufi[wave][pos] = col; }
        cnt += (int)__popcll(m);
    }
    if (cnt > XCAP) cnt = XCAP;
    __syncthreads();
    float cd[4]; int cix[4];
    #pragma unroll
    for (int s = 0; s < 4; ++s) {
        int c = lane + 64*s;
        bool v = c < cnt;
        cd[s]  = v ? bufd[wave][c] : 3.0e38f;
        cix[s] = v ? bufi[wave][c] : 0x7fffffff;
    }
    for (int r = 0; r < KSEL; ++r) {
        float lv = cd[0]; int li_ = cix[0];
        #pragma unroll
        for (int s = 1; s < 4; ++s) {
            if (cd[s] < lv || (cd[s] == lv && cix[s] < li_)) { lv = cd[s]; li_ = cix[s]; }
        }
        float wv = lv; int wi = li_;
        #pragma unroll
        for (int s = 1; s < 64; s <<= 1) {
            float ov = __shfl_xor(wv, s); int oi = __shfl_xor(wi, s);
            if (ov < wv || (ov == wv && oi < wi)) { wv = ov; wi = oi; }
        }
        if (lane == 0) {
            int safe = ((unsigned)wi < (unsigned)n) ? wi : ((row + 1) & (n - 1));
            out_idx[row*KSEL + r] = safe;
        }
        #pragma unroll
        for (int s = 0; s < 4; ++s) {
            if (cd[s] == wv && cix[s] == wi) { cd[s] = 3.0e38f; cix[s] = 0x7fffffff; }
        }
    }
}

// ---------------- EdgeConv: 1 wave/point; stage all edges, stream w2 once ----------
template<int H1, int H2, int KN, int SELF>
__global__ void edge_mlp_kernel(const float* __restrict__ u, const float* __restrict__ v,
                                const float* __restrict__ w2, const float* __restrict__ b2,
                                const int* __restrict__ idx, float* __restrict__ out, int npts) {
    constexpr int E  = KN + SELF;
    constexpr int NT = (H1 + 63) / 64;
    constexpr int NC = (H2 + 63) / 64;
    __shared__ __align__(16) float st[E][H1];
    int i = blockIdx.x;
    int lane = threadIdx.x; // 64 threads
    float suh[NT];
    #pragma unroll
    for (int t = 0; t < NT; ++t) {
        int h = lane + 64*t;
        suh[t] = (h < H1) ? u[(size_t)i*H1 + h] : 0.f;
    }
    #pragma unroll
    for (int e = 0; e < E; ++e) {
        int j = (SELF && e == 0) ? i : idx[i*KN + (e - SELF)];
        j = ((unsigned)j < (unsigned)npts) ? j : i;   // structural safety
        #pragma unroll
        for (int t = 0; t < NT; ++t) {
            int h = lane + 64*t;
            if (h < H1) st[e][h] = frelu(suh[t] + v[(size_t)j*H1 + h]);
        }
    }
    __syncthreads();
    float acc[E][NC];
    #pragma unroll
    for (int e = 0; e < E; ++e) {
        #pragma unroll
        for (int c = 0; c < NC; ++c) acc[e][c] = 0.f;
    }
    for (int h0 = 0; h0 < H1; h0 += 4) {
        float wv[NC][4];
        #pragma unroll
        for (int c = 0; c < NC; ++c) {
            int col = lane + 64*c;
            #pragma unroll
            for (int q = 0; q < 4; ++q) {
                wv[c][q] = (col < H2) ? w2[(size_t)(h0+q)*H2 + col] : 0.f;
            }
        }
        #pragma unroll
        for (int e = 0; e < E; ++e) {
            float4 s4 = *(const float4*)&st[e][h0];
            #pragma unroll
            for (int c = 0; c < NC; ++c) {
                acc[e][c] += s4.x*wv[c][0] + s4.y*wv[c][1] + s4.z*wv[c][2] + s4.w*wv[c][3];
            }
        }
    }
    #pragma unroll
    for (int c = 0; c < NC; ++c) {
        int col = lane + 64*c;
        if (col < H2) {
            float best = acc[0][c];
            #pragma unroll
            for (int e = 1; e < E; ++e) best = fmaxf(best, acc[e][c]);
            out[(size_t)i*H2 + col] = best + b2[col];
        }
    }
}

// ---------------- refiner EdgeConv (H1=384, H2=3), wave per point ------------------
__global__ void edge_ref_kernel(const float* __restrict__ ur, const float* __restrict__ vr,
                                const float* __restrict__ w2, const float* __restrict__ b2,
                                const int* __restrict__ idx,
                                const float* __restrict__ xyz_in, float* __restrict__ out, int n) {
    int wave = threadIdx.x >> 6, lane = threadIdx.x & 63;
    int i = blockIdx.x*4 + wave;
    if (i >= n) return;
    float m0 = -3.0e38f, m1 = -3.0e38f, m2 = -3.0e38f;
    float uh[6];
    #pragma unroll
    for (int t = 0; t < 6; ++t) uh[t] = ur[(size_t)i*384 + lane + 64*t];
    for (int e = 0; e < KRR; ++e) {
        int j = idx[i*KRR + e];
        j = ((unsigned)j < (unsigned)n) ? j : i;      // structural safety
        float a0 = 0.f, a1 = 0.f, a2 = 0.f;
        #pragma unroll
        for (int t = 0; t < 6; ++t) {
            int h = lane + 64*t;
            float tv = frelu(uh[t] + vr[(size_t)j*384 + h]);
            a0 += tv*w2[h*3+0]; a1 += tv*w2[h*3+1]; a2 += tv*w2[h*3+2];
        }
        #pragma unroll
        for (int s = 32; s > 0; s >>= 1) {
            a0 += __shfl_xor(a0, s); a1 += __shfl_xor(a1, s); a2 += __shfl_xor(a2, s);
        }
        m0 = fmaxf(m0, a0 + b2[0]); m1 = fmaxf(m1, a1 + b2[1]); m2 = fmaxf(m2, a2 + b2[2]);
    }
    if (lane == 0) {
        out[i*3+0] = xyz_in[i*3+0] + m0;
        out[i*3+1] = xyz_in[i*3+1] + m1;
        out[i*3+2] = xyz_in[i*3+2] + m2;
    }
}

// ---------------- target xyz: repeat(pred,4) + 0.02*noise --------------------------
__global__ void tgt0_kernel(const float* __restrict__ pred_xyz, const float* __restrict__ noise,
                            float* __restrict__ xyz0) {
    int i = blockIdx.x*256 + threadIdx.x;
    if (i >= N8*3) return;
    int pt = i/3, c = i - pt*3;
    int b = pt >> 11, r = pt & 2047, p = r >> 2;
    xyz0[i] = pred_xyz[(b*PDIM + p)*3 + c] + 0.02f*noise[i];
}

// ---------------- folding MLP: 99 -> 256 -> 256 -> 3 residual ----------------------
__global__ void fold_kernel(const float* __restrict__ xyz0, const float* __restrict__ featd,
                            const float* __restrict__ w1, const float* __restrict__ b1,
                            const float* __restrict__ w2, const float* __restrict__ b2,
                            const float* __restrict__ w3, const float* __restrict__ b3,
                            float* __restrict__ xyz1) {
    const int PTS = 16;
    int base = blockIdx.x * PTS;
    int tid = threadIdx.x;
    __shared__ __align__(16) float xin[PTS][100];
    __shared__ __align__(16) float h1[PTS][FOLDH];
    __shared__ __align__(16) float h2s[PTS][FOLDH];
    for (int t = tid; t < PTS*100; t += 256) {
        int pt = t/100, k = t - pt*100;
        int gi = base + pt;
        float vv = 0.f;
        if (k < 3) vv = xyz0[gi*3 + k];
        else if (k < 99) {
            int b = gi >> 11, p = (gi & 2047) >> 2;
            vv = featd[(b*PDIM + p)*H2C + (k - 3)];
        }
        xin[pt][k] = vv;
    }
    __syncthreads();
    int c = tid;
    float acc[PTS];
    #pragma unroll
    for (int pt = 0; pt < PTS; ++pt) acc[pt] = b1[c];
    for (int k0 = 0; k0 < 96; k0 += 4) {
        float wa = w1[(k0+0)*FOLDH + c], wb = w1[(k0+1)*FOLDH + c];
        float wc = w1[(k0+2)*FOLDH + c], wd = w1[(k0+3)*FOLDH + c];
        #pragma unroll
        for (int pt = 0; pt < PTS; ++pt) {
            float4 xv = *(const float4*)&xin[pt][k0];
            acc[pt] += xv.x*wa + xv.y*wb + xv.z*wc + xv.w*wd;
        }
    }
    {
        float wa = w1[96*FOLDH + c], wb = w1[97*FOLDH + c], wc = w1[98*FOLDH + c];
        #pragma unroll
        for (int pt = 0; pt < PTS; ++pt) {
            float4 xv = *(const float4*)&xin[pt][96];
            acc[pt] += xv.x*wa + xv.y*wb + xv.z*wc;
        }
    }
    #pragma unroll
    for (int pt = 0; pt < PTS; ++pt) h1[pt][c] = frelu(acc[pt]);
    __syncthreads();
    #pragma unroll
    for (int pt = 0; pt < PTS; ++pt) acc[pt] = b2[c];
    for (int k0 = 0; k0 < FOLDH; k0 += 4) {
        float wa = w2[(k0+0)*FOLDH + c], wb = w2[(k0+1)*FOLDH + c];
        float wc = w2[(k0+2)*FOLDH + c], wd = w2[(k0+3)*FOLDH + c];
        #pragma unroll
        for (int pt = 0; pt < PTS; ++pt) {
            float4 hv = *(const float4*)&h1[pt][k0];
            acc[pt] += hv.x*wa + hv.y*wb + hv.z*wc + hv.w*wd;
        }
    }
    #pragma unroll
    for (int pt = 0; pt < PTS; ++pt) h2s[pt][c] = frelu(acc[pt]);
    __syncthreads();
    if (tid < PTS*3) {
        int pt = tid/3, cc = tid - pt*3;
        float a = b3[cc];
        for (int k0 = 0; k0 < FOLDH; k0 += 4) {
            float4 hv = *(const float4*)&h2s[pt][k0];
            a += hv.x*w3[(k0+0)*3+cc] + hv.y*w3[(k0+1)*3+cc] + hv.z*w3[(k0+2)*3+cc] + hv.w*w3[(k0+3)*3+cc];
        }
        int gi = base + pt;
        xyz1[gi*3 + cc] = xyz0[gi*3 + cc] + a;
    }
}

// ---------------- ctx deform head: xyz + 0.05 * mlp2(feat) -------------------------
__global__ void cdef_kernel(const float* __restrict__ feat, const float* __restrict__ w1,
                            const float* __restrict__ b1, const float* __restrict__ w2,
                            const float* __restrict__ b2, const float* __restrict__ ctx_xyz,
                            float* __restrict__ out) {
    int i = blockIdx.x;
    int tid = threadIdx.x; // 128
    __shared__ float sf[H2C], st[H2C];
    if (tid < H2C) sf[tid] = feat[(size_t)i*H2C + tid];
    __syncthreads();
    if (tid < H2C) {
        float acc = b1[tid];
        for (int k = 0; k < H2C; ++k) acc += sf[k]*w1[k*H2C + tid];
        st[tid] = frelu(acc);
    }
    __syncthreads();
    if (tid < 3) {
        float acc = b2[tid];
        for (int k = 0; k < H2C; ++k) acc += st[k]*w2[k*3 + tid];
        out[i*3 + tid] = ctx_xyz[i*3 + tid] + 0.05f*acc;
    }
}

// ---------------- xcat = [tgt_feat(96), tgt_xyz(3)] --------------------------------
__global__ void xcat_kernel(const float* __restrict__ featd, const float* __restrict__ xyz1,
                            float* __restrict__ xcat) {
    int i = blockIdx.x*256 + threadIdx.x;
    if (i >= N8*99) return;
    int pt = i/99, k = i - pt*99;
    float v;
    if (k < 96) {
        int b = pt >> 11, p = (pt & 2047) >> 2;
        v = featd[(b*PDIM + p)*H2C + k];
    } else {
        v = xyz1[pt*3 + (k - 96)];
    }
    xcat[i] = v;
}

extern "C" void kernel_launch(void* const* d_in, const int* in_sizes, int n_in,
                              void* d_out, int out_size, void* d_ws, size_t ws_size,
                              hipStream_t stream) {
    const float* ctx_xyz    = (const float*)d_in[0];
    const float* ctx_tokens = (const float*)d_in[1];
    const float* pred_xyz   = (const float*)d_in[2];
    const float* noise      = (const float*)d_in[4];
    const float* c1w1 = (const float*)d_in[5];
    const float* c1b1 = (const float*)d_in[6];
    const float* c1w2 = (const float*)d_in[7];
    const float* c1b2 = (const float*)d_in[8];
    const float* c2w1 = (const float*)d_in[9];
    const float* c2b1 = (const float*)d_in[10];
    const float* c2w2 = (const float*)d_in[11];
    const float* c2b2 = (const float*)d_in[12];
    const float* cdw1 = (const float*)d_in[13];
    const float* cdb1 = (const float*)d_in[14];
    const float* cdw2 = (const float*)d_in[15];
    const float* cdb2 = (const float*)d_in[16];
    const float* fw1  = (const float*)d_in[17];
    const float* fb1  = (const float*)d_in[18];
    const float* fw2  = (const float*)d_in[19];
    const float* fb2  = (const float*)d_in[20];
    const float* fw3  = (const float*)d_in[21];
    const float* fb3  = (const float*)d_in[22];
    const float* rw1  = (const float*)d_in[23];
    const float* rb1  = (const float*)d_in[24];
    const float* rw2  = (const float*)d_in[25];
    const float* rb2  = (const float*)d_in[26];

    float* W = (float*)d_ws;
    // element offsets (staged aliasing: dist region (W+0) reused by pts then ur/vr)
    float* dist   = W + 0;                   // 2048*2048
    float4* pts   = (float4*)W;              // 8192 float4 (after dist dead)
    float* ur     = W + 0;                   // 8192*384 (after pts consumed)
    float* vr     = W + 3145728;
    float* u1     = W + 4194304;             // 2048*192
    float* v1     = u1 + N2*H1C;
    float* h_ctx  = v1 + N2*H1C;
    float* h_tgt  = h_ctx + N2*H1C;
    float* u2     = h_tgt + N2*H1C;          // 2048*96
    float* v2     = u2 + N2*H2C;
    float* cfeat  = v2 + N2*H2C;
    float* tfeat  = W + 6356992;             // persistent from here
    float* wd1    = tfeat + N2*H2C;          // 384*192
    float* wd2    = wd1 + 384*192;           // 192*96
    float* wdr    = wd2 + 192*96;            // 99*384
    int*   cidx1  = (int*)(wdr + 99*384);    // 2048*16
    int*   tidx1  = cidx1 + N2*16;           // 2048*4
    int*   cidx2  = tidx1 + N2*4;            // 2048*8
    int*   tidx2  = cidx2 + N2*8;            // 2048*2
    int*   ridx   = tidx2 + N2*2;            // 8192*16
    float* sqb    = (float*)(ridx + N8*16);  // 8192
    float* xyz0   = sqb + N8;                // 8192*3
    float* xyz1   = xyz0 + N8*3;             // 8192*3
    float* xcat   = xyz1 + N8*3;             // 8192*99

    float* out_ctx = (float*)d_out;          // rows 0..2047
    float* out_tgt = out_ctx + N2*3;         // rows 2048..10239

    dim3 b16(16,16);

    // --- weight diffs
    matsub_kernel<<<(384*192+255)/256, 256, 0, stream>>>(c1w1, wd1, 384*192);
    matsub_kernel<<<(192*96 +255)/256, 256, 0, stream>>>(c2w1, wd2, 192*96);
    matsub_kernel<<<(99*384 +255)/256, 256, 0, stream>>>(rw1,  wdr, 99*384);

    // --- S1: token distance matrix (shared by ctx knn-16 and tgt distinct knn-4)
    rowsq_kernel<<<N2, 256, 0, stream>>>(ctx_tokens, sqb, N2, CDIM);
    dist64_kernel<<<dim3(N2/64, N2/64), b16, 0, stream>>>(ctx_tokens, sqb, dist, N2, CDIM);
    knn_dist2_kernel<16><<<N2/4, 256, 0, stream>>>(dist, N2, cidx1);
    knn_dist2_kernel<4> <<<N2/4, 256, 0, stream>>>(dist, N2, tidx1);

    // --- S2: conv1
    gemm64_kernel<<<dim3(3, N2/64), b16, 0, stream>>>(ctx_tokens, wd1, c1b1, u1, H1C, CDIM);
    gemm64_kernel<<<dim3(3, N2/64), b16, 0, stream>>>(ctx_tokens, c1w1 + 384*192, nullptr, v1, H1C, CDIM);
    edge_mlp_kernel<192,192,16,0><<<N2, 64, 0, stream>>>(u1, v1, c1w2, c1b2, cidx1, h_ctx, N2);
    edge_mlp_kernel<192,192,4, 1><<<N2, 64, 0, stream>>>(u1, v1, c1w2, c1b2, tidx1, h_tgt, N2);

    // --- S3: ctx conv2 + deform head
    rowsq_kernel<<<N2, 256, 0, stream>>>(h_ctx, sqb, N2, H1C);
    dist64_kernel<<<dim3(N2/64, N2/64), b16, 0, stream>>>(h_ctx, sqb, dist, N2, H1C);
    knn_dist2_kernel<8><<<N2/4, 256, 0, stream>>>(dist, N2, cidx2);
    gemm64_kernel<<<dim3(2, N2/64), b16, 0, stream>>>(h_ctx, wd2, c2b1, u2, H2C, H1C);
    gemm64_kernel<<<dim3(2, N2/64), b16, 0, stream>>>(h_ctx, c2w1 + 192*96, nullptr, v2, H2C, H1C);
    edge_mlp_kernel<96,96,8,0><<<N2, 64, 0, stream>>>(u2, v2, c2w2, c2b2, cidx2, cfeat, N2);
    cdef_kernel<<<N2, 128, 0, stream>>>(cfeat, cdw1, cdb1, cdw2, cdb2, ctx_xyz, out_ctx);

    // --- S4: tgt conv2 (distinct: self + 2)
    rowsq_kernel<<<N2, 256, 0, stream>>>(h_tgt, sqb, N2, H1C);
    dist64_kernel<<<dim3(N2/64, N2/64), b16, 0, stream>>>(h_tgt, sqb, dist, N2, H1C);
    knn_dist2_kernel<2><<<N2/4, 256, 0, stream>>>(dist, N2, tidx2);
    gemm64_kernel<<<dim3(2, N2/64), b16, 0, stream>>>(h_tgt, wd2, c2b1, u2, H2C, H1C);
    gemm64_kernel<<<dim3(2, N2/64), b16, 0, stream>>>(h_tgt, c2w1 + 192*96, nullptr, v2, H2C, H1C);
    edge_mlp_kernel<96,96,2,1><<<N2, 64, 0, stream>>>(u2, v2, c2w2, c2b2, tidx2, tfeat, N2);

    // --- S6: target xyz upsample + folding MLP
    tgt0_kernel<<<(N8*3+255)/256, 256, 0, stream>>>(pred_xyz, noise, xyz0);
    fold_kernel<<<N8/16, 256, 0, stream>>>(xyz0, tfeat, fw1, fb1, fw2, fb2, fw3, fb3, xyz1);

    // --- S7: refiner knn over xyz (dist region is dead -> pts alias)
    pack_xyz_kernel<<<(N8+255)/256, 256, 0, stream>>>(xyz1, pts, N8);
    knn_xyz2_kernel<<<N8/4, 256, 0, stream>>>(pts, N8, ridx);

    // --- S8: refiner EdgeConv (pts dead -> ur alias), residual to output
    xcat_kernel<<<(N8*99+255)/256, 256, 0, stream>>>(tfeat, xyz1, xcat);
    gemm64_kernel<<<dim3(6, N8/64), b16, 0, stream>>>(xcat, wdr, rb1, ur, 384, 99);
    gemm64_kernel<<<dim3(6, N8/64), b16, 0, stream>>>(xcat, rw1 + 99*384, nullptr, vr, 384, 99);
    edge_ref_kernel<<<N8/4, 256, 0, stream>>>(ur, vr, rw2, rb2, ridx, xyz1, out_tgt, N8);
}

// Round 4
// 789.480 us; speedup vs baseline: 2.9152x; 1.0779x over previous
//
#include <hip/hip_runtime.h>

#define N2 2048      // B*P
#define N8 8192      // B*P*UP
#define CDIM 384
#define H1C 192      // C/2
#define H2C 96       // C/4
#define PDIM 512
#define KRR 16
#define FOLDH 256
#define XCAP 256
#define TILE4 1024
#define INFF 3.0e38f

__device__ __forceinline__ float frelu(float x) { return x > 0.f ? x : 0.f; }

// ---------------- row squared norms (wave per row) ---------------------------------
__global__ void rowsq_kernel(const float* __restrict__ x, float* __restrict__ sq, int d) {
    int wave = threadIdx.x >> 6, lane = threadIdx.x & 63;
    int row = blockIdx.x*4 + wave;
    float acc = 0.f;
    for (int k = lane; k < d; k += 64) { float v = x[(size_t)row*d + k]; acc += v*v; }
    #pragma unroll
    for (int s = 1; s < 64; s <<= 1) acc += __shfl_xor(acc, s);
    if (lane == 0) sq[row] = acc;
}

// ---------------- pairwise distance matrix, 64x64 tile, 4x4 micro ------------------
__global__ void dist64_kernel(const float* __restrict__ x, const float* __restrict__ sq,
                              float* __restrict__ dist, int n, int K) {
    __shared__ __align__(16) float As[16][68];
    __shared__ __align__(16) float Bs[16][68];
    int tx = threadIdx.x, ty = threadIdx.y;
    int t = ty*16 + tx;
    int row0 = blockIdx.y*64, col0 = blockIdx.x*64;
    float acc[4][4] = {};
    for (int k0 = 0; k0 < K; k0 += 16) {
        #pragma unroll
        for (int r = 0; r < 4; ++r) {
            int e = t + 256*r; int kk = e & 15, mm = e >> 4;
            As[kk][mm] = x[(size_t)(row0+mm)*K + k0+kk];
            Bs[kk][mm] = x[(size_t)(col0+mm)*K + k0+kk];
        }
        __syncthreads();
        #pragma unroll
        for (int kk = 0; kk < 16; ++kk) {
            float4 a4 = *(const float4*)&As[kk][ty*4];
            float4 b4 = *(const float4*)&Bs[kk][tx*4];
            acc[0][0] += a4.x*b4.x; acc[0][1] += a4.x*b4.y; acc[0][2] += a4.x*b4.z; acc[0][3] += a4.x*b4.w;
            acc[1][0] += a4.y*b4.x; acc[1][1] += a4.y*b4.y; acc[1][2] += a4.y*b4.z; acc[1][3] += a4.y*b4.w;
            acc[2][0] += a4.z*b4.x; acc[2][1] += a4.z*b4.y; acc[2][2] += a4.z*b4.z; acc[2][3] += a4.z*b4.w;
            acc[3][0] += a4.w*b4.x; acc[3][1] += a4.w*b4.y; acc[3][2] += a4.w*b4.z; acc[3][3] += a4.w*b4.w;
        }
        __syncthreads();
    }
    #pragma unroll
    for (int i2 = 0; i2 < 4; ++i2) {
        int row = row0 + ty*4 + i2;
        float sr = sq[row];
        float4 o;
        o.x = sr + sq[col0+tx*4+0] - 2.f*acc[i2][0];
        o.y = sr + sq[col0+tx*4+1] - 2.f*acc[i2][1];
        o.z = sr + sq[col0+tx*4+2] - 2.f*acc[i2][2];
        o.w = sr + sq[col0+tx*4+3] - 2.f*acc[i2][3];
        *(float4*)&dist[(size_t)row*n + col0 + tx*4] = o;
    }
}

// ---------------- GEMM: C = A[rows,K] @ (Bw - BwB)[K,m] (+bias), 64x64 tile --------
// If A == nullptr, gathers A from [featd(96) | xyzg(3)] (refiner xcat), K=99.
__global__ void gemm64_kernel(const float* __restrict__ A,
                              const float* __restrict__ featd, const float* __restrict__ xyzg,
                              const float* __restrict__ Bw, const float* __restrict__ BwB,
                              const float* __restrict__ bias, float* __restrict__ Cout,
                              int m, int K) {
    __shared__ __align__(16) float As[16][68];
    __shared__ __align__(16) float Bs[16][68];
    int tx = threadIdx.x, ty = threadIdx.y;
    int t = ty*16 + tx;
    int row0 = blockIdx.y*64, col0 = blockIdx.x*64;
    float acc[4][4] = {};
    for (int k0 = 0; k0 < K; k0 += 16) {
        #pragma unroll
        for (int r = 0; r < 4; ++r) {
            int e = t + 256*r; int kk = e & 15, mm = e >> 4;
            int k = k0 + kk, grow = row0 + mm;
            float av = 0.f;
            if (k < K) {
                if (A) av = A[(size_t)grow*K + k];
                else if (k < 96) { int b = grow >> 11, p = (grow & 2047) >> 2;
                                   av = featd[(size_t)(b*PDIM + p)*H2C + k]; }
                else av = xyzg[(size_t)grow*3 + (k - 96)];
            }
            As[kk][mm] = av;
        }
        #pragma unroll
        for (int r = 0; r < 4; ++r) {
            int e = t + 256*r; int nn = e & 63, kk = e >> 6;
            int col = col0 + nn, k = k0 + kk;
            float bv = 0.f;
            if (k < K && col < m) {
                bv = Bw[(size_t)k*m + col];
                if (BwB) bv -= BwB[(size_t)k*m + col];
            }
            Bs[kk][nn] = bv;
        }
        __syncthreads();
        #pragma unroll
        for (int kk = 0; kk < 16; ++kk) {
            float4 a4 = *(const float4*)&As[kk][ty*4];
            float4 b4 = *(const float4*)&Bs[kk][tx*4];
            acc[0][0] += a4.x*b4.x; acc[0][1] += a4.x*b4.y; acc[0][2] += a4.x*b4.z; acc[0][3] += a4.x*b4.w;
            acc[1][0] += a4.y*b4.x; acc[1][1] += a4.y*b4.y; acc[1][2] += a4.y*b4.z; acc[1][3] += a4.y*b4.w;
            acc[2][0] += a4.z*b4.x; acc[2][1] += a4.z*b4.y; acc[2][2] += a4.z*b4.z; acc[2][3] += a4.z*b4.w;
            acc[3][0] += a4.w*b4.x; acc[3][1] += a4.w*b4.y; acc[3][2] += a4.w*b4.z; acc[3][3] += a4.w*b4.w;
        }
        __syncthreads();
    }
    #pragma unroll
    for (int i2 = 0; i2 < 4; ++i2) {
        int row = row0 + ty*4 + i2;
        #pragma unroll
        for (int j2 = 0; j2 < 4; ++j2) {
            int col = col0 + tx*4 + j2;
            if (col < m) Cout[(size_t)row*m + col] = acc[i2][j2] + (bias ? bias[col] : 0.f);
        }
    }
}

// ---------------- exact two-phase knn from materialized dist rows ------------------
// Phase A: value-only per-lane min; threshold Tv = KSEL-th smallest lane-min
// (>= true KSEL-th value => collecting dv<=Tv is a superset of true top-KSEL).
// Phase C restores exact (d,col) lexicographic order.
template<int KSEL>
__global__ void knn_dist2_kernel(const float* __restrict__ dist, int n, int* __restrict__ out_idx) {
    int wave = threadIdx.x >> 6, lane = threadIdx.x & 63;
    int row = blockIdx.x*4 + wave;
    __shared__ float bufd[4][XCAP];
    __shared__ int   bufi[4][XCAP];
    __shared__ int   lcnt[4];
    const float4* drow = (const float4*)(dist + (size_t)row*n);
    int nq = n >> 2;
    float mv = INFF;
    for (int i = lane; i < nq; i += 64) {
        float4 d4 = drow[i]; int base = i*4;
        float a = (base+0 == row) ? INFF : d4.x;
        float b = (base+1 == row) ? INFF : d4.y;
        float c = (base+2 == row) ? INFF : d4.z;
        float d = (base+3 == row) ? INFF : d4.w;
        mv = fminf(mv, fminf(fminf(a,b), fminf(c,d)));
    }
    float cv = mv, Tv = INFF;
    for (int r = 0; r < KSEL; ++r) {
        float wv = cv;
        #pragma unroll
        for (int s = 1; s < 64; s <<= 1) wv = fminf(wv, __shfl_xor(wv, s));
        Tv = wv;
        unsigned long long mk = __ballot(cv == wv);
        if (lane == (int)(__ffsll(mk) - 1)) cv = INFF;
    }
    if (lane == 0) lcnt[wave] = 0;
    for (int i = lane; i < nq; i += 64) {
        float4 d4 = drow[i]; int base = i*4;
        float dv4[4] = {d4.x, d4.y, d4.z, d4.w};
        #pragma unroll
        for (int q = 0; q < 4; ++q) {
            int col = base + q;
            if (col != row && dv4[q] <= Tv) {
                int pos = atomicAdd(&lcnt[wave], 1);
                if (pos < XCAP) { bufd[wave][pos] = dv4[q]; bufi[wave][pos] = col; }
            }
        }
    }
    int cnt = lcnt[wave]; if (cnt > XCAP) cnt = XCAP;
    float cd[4]; int cix[4];
    #pragma unroll
    for (int s = 0; s < 4; ++s) {
        int c = lane + 64*s;
        bool v = c < cnt;
        cd[s]  = v ? bufd[wave][c] : INFF;
        cix[s] = v ? bufi[wave][c] : 0x7fffffff;
    }
    for (int r = 0; r < KSEL; ++r) {
        float lv = cd[0]; int li = cix[0];
        #pragma unroll
        for (int s = 1; s < 4; ++s) {
            if (cd[s] < lv || (cd[s] == lv && cix[s] < li)) { lv = cd[s]; li = cix[s]; }
        }
        float wv = lv; int wi = li;
        #pragma unroll
        for (int s = 1; s < 64; s <<= 1) {
            float ov = __shfl_xor(wv, s); int oi = __shfl_xor(wi, s);
            if (ov < wv || (ov == wv && oi < wi)) { wv = ov; wi = oi; }
        }
        if (lane == 0) {
            int safe = ((unsigned)wi < (unsigned)n) ? wi : ((row + 1) & (n - 1));
            out_idx[row*KSEL + r] = safe;
        }
        #pragma unroll
        for (int s = 0; s < 4; ++s) {
            if (cd[s] == wv && cix[s] == wi) { cd[s] = INFF; cix[s] = 0x7fffffff; }
        }
    }
}

// ---------------- exact two-phase knn over packed xyz, LDS-tiled -------------------
__global__ void knn_xyz2_kernel(const float4* __restrict__ pts, int n, int* __restrict__ out_idx) {
    int wave = threadIdx.x >> 6, lane = threadIdx.x & 63;
    int tid = threadIdx.x;
    int row = blockIdx.x*4 + wave;
    __shared__ __align__(16) float4 tile[TILE4];
    __shared__ float bufd[4][XCAP];
    __shared__ int   bufi[4][XCAP];
    __shared__ int   lcnt[4];
    float4 p = pts[row];
    float x0 = p.x, x1 = p.y, x2 = p.z, sr = p.w;
    float mv = INFF;
    for (int t0 = 0; t0 < n; t0 += TILE4) {
        __syncthreads();
        for (int e = tid; e < TILE4; e += 256) tile[e] = pts[t0 + e];
        __syncthreads();
        #pragma unroll 4
        for (int c = lane; c < TILE4; c += 64) {
            float4 q = tile[c];
            int col = t0 + c;
            float dv = sr + q.w - 2.f*(x0*q.x + x1*q.y + x2*q.z);
            dv = (col == row) ? INFF : dv;
            mv = fminf(mv, dv);
        }
    }
    float cv = mv, Tv = INFF;
    for (int r = 0; r < 16; ++r) {
        float wv = cv;
        #pragma unroll
        for (int s = 1; s < 64; s <<= 1) wv = fminf(wv, __shfl_xor(wv, s));
        Tv = wv;
        unsigned long long mk = __ballot(cv == wv);
        if (lane == (int)(__ffsll(mk) - 1)) cv = INFF;
    }
    if (lane == 0) lcnt[wave] = 0;
    for (int t0 = 0; t0 < n; t0 += TILE4) {
        __syncthreads();
        for (int e = tid; e < TILE4; e += 256) tile[e] = pts[t0 + e];
        __syncthreads();
        #pragma unroll 4
        for (int c = lane; c < TILE4; c += 64) {
            float4 q = tile[c];
            int col = t0 + c;
            float dv = sr + q.w - 2.f*(x0*q.x + x1*q.y + x2*q.z);
            if (col != row && dv <= Tv) {
                int pos = atomicAdd(&lcnt[wave], 1);
                if (pos < XCAP) { bufd[wave][pos] = dv; bufi[wave][pos] = col; }
            }
        }
    }
    int cnt = lcnt[wave]; if (cnt > XCAP) cnt = XCAP;
    float cd[4]; int cix[4];
    #pragma unroll
    for (int s = 0; s < 4; ++s) {
        int c = lane + 64*s;
        bool v = c < cnt;
        cd[s]  = v ? bufd[wave][c] : INFF;
        cix[s] = v ? bufi[wave][c] : 0x7fffffff;
    }
    for (int r = 0; r < 16; ++r) {
        float lv = cd[0]; int li = cix[0];
        #pragma unroll
        for (int s = 1; s < 4; ++s) {
            if (cd[s] < lv || (cd[s] == lv && cix[s] < li)) { lv = cd[s]; li = cix[s]; }
        }
        float wv = lv; int wi = li;
        #pragma unroll
        for (int s = 1; s < 64; s <<= 1) {
            float ov = __shfl_xor(wv, s); int oi = __shfl_xor(wi, s);
            if (ov < wv || (ov == wv && oi < wi)) { wv = ov; wi = oi; }
        }
        if (lane == 0) {
            int safe = ((unsigned)wi < (unsigned)n) ? wi : ((row + 1) & (n - 1));
            out_idx[row*16 + r] = safe;
        }
        #pragma unroll
        for (int s = 0; s < 4; ++s) {
            if (cd[s] == wv && cix[s] == wi) { cd[s] = INFF; cix[s] = 0x7fffffff; }
        }
    }
}

// ---------------- EdgeConv: 1 wave/point; optional row-sq + fused cdef head --------
template<int H1, int H2, int KN, int SELF>
__global__ void edge_mlp_kernel(const float* __restrict__ u, const float* __restrict__ v,
                                const float* __restrict__ w2, const float* __restrict__ b2,
                                const int* __restrict__ idx, int idxs,
                                float* __restrict__ out, float* __restrict__ out_sq,
                                const float* __restrict__ cdw1, const float* __restrict__ cdb1,
                                const float* __restrict__ cdw2, const float* __restrict__ cdb2,
                                const float* __restrict__ ctx_xyz, float* __restrict__ out_xyz,
                                int npts) {
    constexpr int E  = KN + SELF;
    constexpr int NT = (H1 + 63) / 64;
    constexpr int NC = (H2 + 63) / 64;
    __shared__ __align__(16) float st[E][H1];
    __shared__ float sf_[96], st2_[96];
    int i = blockIdx.x;
    int lane = threadIdx.x; // 64 threads
    float suh[NT];
    #pragma unroll
    for (int t = 0; t < NT; ++t) {
        int h = lane + 64*t;
        suh[t] = (h < H1) ? u[(size_t)i*H1 + h] : 0.f;
    }
    #pragma unroll
    for (int e = 0; e < E; ++e) {
        int j = (SELF && e == 0) ? i : idx[i*idxs + (e - SELF)];
        j = ((unsigned)j < (unsigned)npts) ? j : i;
        #pragma unroll
        for (int t = 0; t < NT; ++t) {
            int h = lane + 64*t;
            if (h < H1) st[e][h] = frelu(suh[t] + v[(size_t)j*H1 + h]);
        }
    }
    __syncthreads();
    float acc[E][NC];
    #pragma unroll
    for (int e = 0; e < E; ++e) {
        #pragma unroll
        for (int c = 0; c < NC; ++c) acc[e][c] = 0.f;
    }
    for (int h0 = 0; h0 < H1; h0 += 4) {
        float wv[NC][4];
        #pragma unroll
        for (int c = 0; c < NC; ++c) {
            int col = lane + 64*c;
            #pragma unroll
            for (int q = 0; q < 4; ++q) {
                wv[c][q] = (col < H2) ? w2[(size_t)(h0+q)*H2 + col] : 0.f;
            }
        }
        #pragma unroll
        for (int e = 0; e < E; ++e) {
            float4 s4 = *(const float4*)&st[e][h0];
            #pragma unroll
            for (int c = 0; c < NC; ++c) {
                acc[e][c] += s4.x*wv[c][0] + s4.y*wv[c][1] + s4.z*wv[c][2] + s4.w*wv[c][3];
            }
        }
    }
    float vals[NC];
    #pragma unroll
    for (int c = 0; c < NC; ++c) {
        int col = lane + 64*c;
        if (col < H2) {
            float best = acc[0][c];
            #pragma unroll
            for (int e = 1; e < E; ++e) best = fmaxf(best, acc[e][c]);
            vals[c] = best + b2[col];
            if (out) out[(size_t)i*H2 + col] = vals[c];
        } else vals[c] = 0.f;
    }
    if (out_sq) {
        float part = 0.f;
        #pragma unroll
        for (int c = 0; c < NC; ++c) part += vals[c]*vals[c];
        #pragma unroll
        for (int s = 1; s < 64; s <<= 1) part += __shfl_xor(part, s);
        if (lane == 0) out_sq[i] = part;
    }
    if (H2 == 96 && cdw1) {   // fused ctx deform head
        #pragma unroll
        for (int c = 0; c < NC; ++c) {
            int col = lane + 64*c;
            if (col < 96) sf_[col] = vals[c];
        }
        __syncthreads();
        #pragma unroll
        for (int c = 0; c < 2; ++c) {
            int col = lane + 64*c;
            if (col < 96) {
                float a = cdb1[col];
                for (int k = 0; k < 96; ++k) a += sf_[k]*cdw1[k*96 + col];
                st2_[col] = frelu(a);
            }
        }
        __syncthreads();
        float s0 = st2_[lane];
        float p0 = s0*cdw2[lane*3+0], p1 = s0*cdw2[lane*3+1], p2 = s0*cdw2[lane*3+2];
        if (lane < 32) {
            float s1 = st2_[lane+64];
            p0 += s1*cdw2[(lane+64)*3+0];
            p1 += s1*cdw2[(lane+64)*3+1];
            p2 += s1*cdw2[(lane+64)*3+2];
        }
        #pragma unroll
        for (int s = 1; s < 64; s <<= 1) {
            p0 += __shfl_xor(p0, s); p1 += __shfl_xor(p1, s); p2 += __shfl_xor(p2, s);
        }
        if (lane == 0) {
            out_xyz[i*3+0] = ctx_xyz[i*3+0] + 0.05f*(cdb2[0] + p0);
            out_xyz[i*3+1] = ctx_xyz[i*3+1] + 0.05f*(cdb2[1] + p1);
            out_xyz[i*3+2] = ctx_xyz[i*3+2] + 0.05f*(cdb2[2] + p2);
        }
    }
}

// ---------------- refiner EdgeConv (H1=384, H2=3), wave per point ------------------
__global__ void edge_ref_kernel(const float* __restrict__ ur, const float* __restrict__ vr,
                                const float* __restrict__ w2, const float* __restrict__ b2,
                                const int* __restrict__ idx,
                                const float* __restrict__ xyz_in, float* __restrict__ out, int n) {
    int wave = threadIdx.x >> 6, lane = threadIdx.x & 63;
    int i = blockIdx.x*4 + wave;
    if (i >= n) return;
    float m0 = -INFF, m1 = -INFF, m2 = -INFF;
    float uh[6];
    #pragma unroll
    for (int t = 0; t < 6; ++t) uh[t] = ur[(size_t)i*384 + lane + 64*t];
    for (int e = 0; e < KRR; ++e) {
        int j = idx[i*KRR + e];
        j = ((unsigned)j < (unsigned)n) ? j : i;
        float a0 = 0.f, a1 = 0.f, a2 = 0.f;
        #pragma unroll
        for (int t = 0; t < 6; ++t) {
            int h = lane + 64*t;
            float tv = frelu(uh[t] + vr[(size_t)j*384 + h]);
            a0 += tv*w2[h*3+0]; a1 += tv*w2[h*3+1]; a2 += tv*w2[h*3+2];
        }
        #pragma unroll
        for (int s = 32; s > 0; s >>= 1) {
            a0 += __shfl_xor(a0, s); a1 += __shfl_xor(a1, s); a2 += __shfl_xor(a2, s);
        }
        m0 = fmaxf(m0, a0 + b2[0]); m1 = fmaxf(m1, a1 + b2[1]); m2 = fmaxf(m2, a2 + b2[2]);
    }
    if (lane == 0) {
        out[i*3+0] = xyz_in[i*3+0] + m0;
        out[i*3+1] = xyz_in[i*3+1] + m1;
        out[i*3+2] = xyz_in[i*3+2] + m2;
    }
}

// ---------------- folding MLP, fused upsample+noise in, xyz1 + packed pts out ------
__global__ void fold_kernel(const float* __restrict__ pred_xyz, const float* __restrict__ noise,
                            const float* __restrict__ featd,
                            const float* __restrict__ w1, const float* __restrict__ b1,
                            const float* __restrict__ w2, const float* __restrict__ b2,
                            const float* __restrict__ w3, const float* __restrict__ b3,
                            float* __restrict__ xyz1, float4* __restrict__ pts_out) {
    const int PTS = 16;
    int base = blockIdx.x * PTS;
    int tid = threadIdx.x;
    __shared__ __align__(16) float xin[PTS][100];
    __shared__ __align__(16) float h1[PTS][FOLDH];
    __shared__ __align__(16) float h2s[PTS][FOLDH];
    __shared__ float oxyz[PTS][3];
    for (int t = tid; t < PTS*100; t += 256) {
        int pt = t/100, k = t - pt*100;
        int gi = base + pt;
        float vv = 0.f;
        if (k < 3) {
            int b = gi >> 11, p = (gi & 2047) >> 2;
            vv = pred_xyz[(size_t)(b*PDIM + p)*3 + k] + 0.02f*noise[(size_t)gi*3 + k];
        } else if (k < 99) {
            int b = gi >> 11, p = (gi & 2047) >> 2;
            vv = featd[(size_t)(b*PDIM + p)*H2C + (k - 3)];
        }
        xin[pt][k] = vv;
    }
    __syncthreads();
    int c = tid;
    float acc[PTS];
    #pragma unroll
    for (int pt = 0; pt < PTS; ++pt) acc[pt] = b1[c];
    for (int k0 = 0; k0 < 96; k0 += 4) {
        float wa = w1[(k0+0)*FOLDH + c], wb = w1[(k0+1)*FOLDH + c];
        float wc = w1[(k0+2)*FOLDH + c], wd = w1[(k0+3)*FOLDH + c];
        #pragma unroll
        for (int pt = 0; pt < PTS; ++pt) {
            float4 xv = *(const float4*)&xin[pt][k0];
            acc[pt] += xv.x*wa + xv.y*wb + xv.z*wc + xv.w*wd;
        }
    }
    {
        float wa = w1[96*FOLDH + c], wb = w1[97*FOLDH + c], wc = w1[98*FOLDH + c];
        #pragma unroll
        for (int pt = 0; pt < PTS; ++pt) {
            float4 xv = *(const float4*)&xin[pt][96];
            acc[pt] += xv.x*wa + xv.y*wb + xv.z*wc;
        }
    }
    #pragma unroll
    for (int pt = 0; pt < PTS; ++pt) h1[pt][c] = frelu(acc[pt]);
    __syncthreads();
    #pragma unroll
    for (int pt = 0; pt < PTS; ++pt) acc[pt] = b2[c];
    for (int k0 = 0; k0 < FOLDH; k0 += 4) {
        float wa = w2[(k0+0)*FOLDH + c], wb = w2[(k0+1)*FOLDH + c];
        float wc = w2[(k0+2)*FOLDH + c], wd = w2[(k0+3)*FOLDH + c];
        #pragma unroll
        for (int pt = 0; pt < PTS; ++pt) {
            float4 hv = *(const float4*)&h1[pt][k0];
            acc[pt] += hv.x*wa + hv.y*wb + hv.z*wc + hv.w*wd;
        }
    }
    #pragma unroll
    for (int pt = 0; pt < PTS; ++pt) h2s[pt][c] = frelu(acc[pt]);
    __syncthreads();
    if (tid < PTS*3) {
        int pt = tid/3, cc = tid - pt*3;
        float a = b3[cc];
        for (int k0 = 0; k0 < FOLDH; k0 += 4) {
            float4 hv = *(const float4*)&h2s[pt][k0];
            a += hv.x*w3[(k0+0)*3+cc] + hv.y*w3[(k0+1)*3+cc] + hv.z*w3[(k0+2)*3+cc] + hv.w*w3[(k0+3)*3+cc];
        }
        int gi = base + pt;
        float res = xin[pt][cc] + a;
        xyz1[(size_t)gi*3 + cc] = res;
        oxyz[pt][cc] = res;
    }
    __syncthreads();
    if (tid < PTS) {
        float x = oxyz[tid][0], y = oxyz[tid][1], z = oxyz[tid][2];
        pts_out[base + tid] = make_float4(x, y, z, x*x + y*y + z*z);
    }
}

extern "C" void kernel_launch(void* const* d_in, const int* in_sizes, int n_in,
                              void* d_out, int out_size, void* d_ws, size_t ws_size,
                              hipStream_t stream) {
    const float* ctx_xyz    = (const float*)d_in[0];
    const float* ctx_tokens = (const float*)d_in[1];
    const float* pred_xyz   = (const float*)d_in[2];
    const float* noise      = (const float*)d_in[4];
    const float* c1w1 = (const float*)d_in[5];
    const float* c1b1 = (const float*)d_in[6];
    const float* c1w2 = (const float*)d_in[7];
    const float* c1b2 = (const float*)d_in[8];
    const float* c2w1 = (const float*)d_in[9];
    const float* c2b1 = (const float*)d_in[10];
    const float* c2w2 = (const float*)d_in[11];
    const float* c2b2 = (const float*)d_in[12];
    const float* cdw1 = (const float*)d_in[13];
    const float* cdb1 = (const float*)d_in[14];
    const float* cdw2 = (const float*)d_in[15];
    const float* cdb2 = (const float*)d_in[16];
    const float* fw1  = (const float*)d_in[17];
    const float* fb1  = (const float*)d_in[18];
    const float* fw2  = (const float*)d_in[19];
    const float* fb2  = (const float*)d_in[20];
    const float* fw3  = (const float*)d_in[21];
    const float* fb3  = (const float*)d_in[22];
    const float* rw1  = (const float*)d_in[23];
    const float* rb1  = (const float*)d_in[24];
    const float* rw2  = (const float*)d_in[25];
    const float* rb2  = (const float*)d_in[26];

    float* W = (float*)d_ws;
    // region A (aliased over time): dist (S1/S3/S4) -> pts (S6/S7) -> ur (S8)
    float* dist = W;                          // 2048*2048 = 4,194,304
    float4* pts = (float4*)W;                 // 8192 float4
    float* ur   = W;                          // 8192*384 = 3,145,728
    float* vr   = W + 3145728;                // ..6,291,456 (written S8; overlaps only dead bufs)
    // region T (transient, dead before vr is written)
    float* u1    = W + 4194304;               // 2048*192
    float* v1    = u1 + N2*H1C;
    float* h_ctx = v1 + N2*H1C;
    float* h_tgt = h_ctx + N2*H1C;
    float* u2    = h_tgt + N2*H1C;            // 2048*96
    float* v2    = u2 + N2*H2C;               // ends 6,160,384
    // region P (persistent past vr): starts at 6,291,456
    float* tfeat   = W + 6291456;             // 2048*96
    float* sqb     = tfeat + N2*H2C;          // 2048
    float* sq_hctx = sqb + N2;
    float* sq_htgt = sq_hctx + N2;
    float* xyz1    = sq_htgt + N2;            // 8192*3
    int*   cidx1   = (int*)(xyz1 + N8*3);     // 2048*16
    int*   cidx2   = cidx1 + N2*16;           // 2048*8
    int*   tidx2   = cidx2 + N2*8;            // 2048*2
    int*   ridx    = tidx2 + N2*2;            // 8192*16

    float* out_ctx = (float*)d_out;           // rows 0..2047
    float* out_tgt = out_ctx + N2*3;          // rows 2048..10239

    dim3 b16(16,16);
    const float* NUL = nullptr;

    // --- S1: token distance matrix; top-16 (tidx1 == first 4 of cidx1)
    rowsq_kernel<<<N2/4, 256, 0, stream>>>(ctx_tokens, sqb, CDIM);
    dist64_kernel<<<dim3(N2/64, N2/64), b16, 0, stream>>>(ctx_tokens, sqb, dist, N2, CDIM);
    knn_dist2_kernel<16><<<N2/4, 256, 0, stream>>>(dist, N2, cidx1);

    // --- S2: conv1 (u = tok@(W1a-W1b)+b, v = tok@W1b)
    gemm64_kernel<<<dim3(3, N2/64), b16, 0, stream>>>(ctx_tokens, NUL, NUL, c1w1, c1w1 + 384*192, c1b1, u1, H1C, CDIM);
    gemm64_kernel<<<dim3(3, N2/64), b16, 0, stream>>>(ctx_tokens, NUL, NUL, c1w1 + 384*192, NUL, NUL, v1, H1C, CDIM);
    edge_mlp_kernel<192,192,16,0><<<N2, 64, 0, stream>>>(u1, v1, c1w2, c1b2, cidx1, 16, h_ctx, sq_hctx,
                                                         NUL, NUL, NUL, NUL, NUL, nullptr, N2);
    edge_mlp_kernel<192,192,4, 1><<<N2, 64, 0, stream>>>(u1, v1, c1w2, c1b2, cidx1, 16, h_tgt, sq_htgt,
                                                         NUL, NUL, NUL, NUL, NUL, nullptr, N2);

    // --- S3: ctx conv2 + fused deform head
    dist64_kernel<<<dim3(N2/64, N2/64), b16, 0, stream>>>(h_ctx, sq_hctx, dist, N2, H1C);
    knn_dist2_kernel<8><<<N2/4, 256, 0, stream>>>(dist, N2, cidx2);
    gemm64_kernel<<<dim3(2, N2/64), b16, 0, stream>>>(h_ctx, NUL, NUL, c2w1, c2w1 + 192*96, c2b1, u2, H2C, H1C);
    gemm64_kernel<<<dim3(2, N2/64), b16, 0, stream>>>(h_ctx, NUL, NUL, c2w1 + 192*96, NUL, NUL, v2, H2C, H1C);
    edge_mlp_kernel<96,96,8,0><<<N2, 64, 0, stream>>>(u2, v2, c2w2, c2b2, cidx2, 8, nullptr, nullptr,
                                                      cdw1, cdb1, cdw2, cdb2, ctx_xyz, out_ctx, N2);

    // --- S4: tgt conv2 (distinct: self + 2)
    dist64_kernel<<<dim3(N2/64, N2/64), b16, 0, stream>>>(h_tgt, sq_htgt, dist, N2, H1C);
    knn_dist2_kernel<2><<<N2/4, 256, 0, stream>>>(dist, N2, tidx2);
    gemm64_kernel<<<dim3(2, N2/64), b16, 0, stream>>>(h_tgt, NUL, NUL, c2w1, c2w1 + 192*96, c2b1, u2, H2C, H1C);
    gemm64_kernel<<<dim3(2, N2/64), b16, 0, stream>>>(h_tgt, NUL, NUL, c2w1 + 192*96, NUL, NUL, v2, H2C, H1C);
    edge_mlp_kernel<96,96,2,1><<<N2, 64, 0, stream>>>(u2, v2, c2w2, c2b2, tidx2, 2, tfeat, nullptr,
                                                      NUL, NUL, NUL, NUL, NUL, nullptr, N2);

    // --- S6: folding MLP (fused upsample+noise; emits xyz1 + packed pts)
    fold_kernel<<<N8/16, 256, 0, stream>>>(pred_xyz, noise, tfeat, fw1, fb1, fw2, fb2, fw3, fb3, xyz1, pts);

    // --- S7: refiner knn over xyz
    knn_xyz2_kernel<<<N8/4, 256, 0, stream>>>(pts, N8, ridx);

    // --- S8: refiner EdgeConv (A gathered from [tfeat|xyz1]), residual to output
    gemm64_kernel<<<dim3(6, N8/64), b16, 0, stream>>>(NUL, tfeat, xyz1, rw1, rw1 + 99*384, rb1, ur, 384, 99);
    gemm64_kernel<<<dim3(6, N8/64), b16, 0, stream>>>(NUL, tfeat, xyz1, rw1 + 99*384, NUL, NUL, vr, 384, 99);
    edge_ref_kernel<<<N8/4, 256, 0, stream>>>(ur, vr, rw2, rb2, ridx, xyz1, out_tgt, N8);
}